// Round 1
// baseline (185.416 us; speedup 1.0000x reference)
//
#include <hip/hip_runtime.h>
#include <math.h>

#define BB 64
#define II 512
#define HH 2048
#define RR 64

// d_out float offsets
#define OUT_HNEW 0
#define OUT_U    131072
#define OUT_EM   8519680
#define OUT_EV   8552448
#define OUT_AT   8585216
#define OUT_SUR  8585280

// ws float offsets
#define WS_XMAG   0
#define WS_EVMEAN 64
#define WS_ERRSQ  128
#define WS_COEF_A 192
#define WS_COEF_B 256
#define WS_SUR    320
#define WS_CU     384
#define WS_CT     448
#define WS_CH     512
#define WS_FRO2   576
#define WS_EVEC   640
#define WS_PRED   (WS_EVEC + BB*RR)      // 4736
#define WS_ERR    (WS_PRED + BB*II)      // 37504
#define WS_XN     (WS_ERR + BB*II)       // 70272

__device__ __forceinline__ float wave_reduce_sum(float v) {
    #pragma unroll
    for (int o = 32; o > 0; o >>= 1) v += __shfl_down(v, o, 64);
    return v;
}

// x_pred partial dot: pred[b,i] += sum_k h[b,k]*C[i,k] over one k-chunk
__global__ __launch_bounds__(256) void k_pred(const float* __restrict__ h,
                                              const float* __restrict__ C,
                                              float* __restrict__ pred) {
    int it = blockIdx.x & 63;      // i-tile (8 i's)
    int kc = blockIdx.x >> 6;      // k-chunk 0..3 (512 each)
    int b  = threadIdx.x & 63;
    int ig = threadIdx.x >> 6;     // 0..3
    int i0 = it * 8 + ig * 2;
    int k0 = kc * 512;
    const float4* hp = (const float4*)(h + b * HH + k0);
    const float4* c0 = (const float4*)(C + i0 * HH + k0);
    const float4* c1 = (const float4*)(C + (i0 + 1) * HH + k0);
    float a0 = 0.f, a1 = 0.f;
    #pragma unroll 4
    for (int t = 0; t < 128; ++t) {
        float4 hv = hp[t];
        float4 u  = c0[t];
        float4 w  = c1[t];
        a0 += hv.x*u.x + hv.y*u.y + hv.z*u.z + hv.w*u.w;
        a1 += hv.x*w.x + hv.y*w.y + hv.z*w.z + hv.w*w.w;
    }
    atomicAdd(&pred[b * II + i0],     a0);
    atomicAdd(&pred[b * II + i0 + 1], a1);
}

// Per-batch-row: x_mag, error, x_norm, em_new, ev_new, errsq, ev_mean, eV
__global__ __launch_bounds__(256) void k_combine(const float* __restrict__ x,
    const float* __restrict__ error_mean, const float* __restrict__ error_var,
    const float* __restrict__ V, float* __restrict__ ws, float* __restrict__ out)
{
    __shared__ float red[9];
    __shared__ float err_lds[II];
    __shared__ float pr[4][RR];
    int b = blockIdx.x, t = threadIdx.x;
    int lane = t & 63, wid = t >> 6;
    const float* xr  = x + b * II;
    const float* emr = error_mean + b * II;
    const float* evr = error_var + b * II;
    float x1 = xr[t], x2 = xr[t + 256];
    float ev1 = evr[t], ev2 = evr[t + 256];
    float sx  = wave_reduce_sum(x1 * x1 + x2 * x2);
    float sev = wave_reduce_sum(ev1 + ev2);
    if (lane == 0) { red[wid] = sx; red[4 + wid] = sev; }
    __syncthreads();
    if (t == 0) {
        float xm = sqrtf(red[0] + red[1] + red[2] + red[3]);
        ws[WS_XMAG + b] = xm;
        ws[WS_EVMEAN + b] = (red[4] + red[5] + red[6] + red[7]) * (1.0f / II);
        red[8] = xm;
    }
    __syncthreads();
    float xmag = red[8];
    float inv = 1.0f / (xmag + 1e-6f);
    float* err_ws = ws + WS_ERR + b * II;
    float* xn_ws  = ws + WS_XN + b * II;
    float* em_out = out + OUT_EM + b * II;
    float* ev_out = out + OUT_EV + b * II;
    const float* pred = ws + WS_PRED + b * II;
    float serr = 0.f;
    #pragma unroll
    for (int s = 0; s < 2; ++s) {
        int i = t + s * 256;
        float xv  = (s == 0) ? x1 : x2;
        float evv = (s == 0) ? ev1 : ev2;
        float err = xv - tanhf(pred[i]) * xmag;
        err_lds[i] = err;
        err_ws[i]  = err;
        float xn = xv * inv;
        xn = fminf(fmaxf(xn, -1.f), 1.f);
        xn_ws[i] = xn;
        float em_new = 0.95f * emr[i] + 0.05f * err;
        em_out[i] = em_new;
        float d = err - em_new;
        ev_out[i] = 0.95f * evv + 0.05f * d * d;
        serr += err * err;
    }
    serr = wave_reduce_sum(serr);
    if (lane == 0) red[wid] = serr;
    __syncthreads();            // also publishes err_lds
    if (t == 0) ws[WS_ERRSQ + b] = red[0] + red[1] + red[2] + red[3];
    // eV[b,r] = sum_i err[i] * V[i,r]
    int r = t & 63, kg = t >> 6;
    float p = 0.f;
    const float* Vp = V + r;
    int base = kg * 128;
    #pragma unroll 4
    for (int j = 0; j < 128; ++j) p += err_lds[base + j] * Vp[(base + j) * RR];
    pr[kg][r] = p;
    __syncthreads();
    if (kg == 0) ws[WS_EVEC + b * RR + r] = pr[0][r] + pr[1][r] + pr[2][r] + pr[3][r];
}

// Per-batch scalars
__global__ void k_scalars(const float* __restrict__ adaptive_tau,
                          const float* __restrict__ eta_p,
                          const float* __restrict__ tau_sys_p,
                          const float* __restrict__ lls_p,
                          float* __restrict__ ws, float* __restrict__ out)
{
    int b = threadIdx.x;
    if (b >= BB) return;
    float xm  = ws[WS_XMAG + b];
    float rel = sqrtf(ws[WS_ERRSQ + b]) / (xm + 1e-6f);
    float ent = 0.5f * logf(17.07946844534713f * (ws[WS_EVMEAN + b] + 1e-6f));
    ent = fminf(fmaxf(ent, 0.f), 2.f);
    float nat = fminf(0.999f * adaptive_tau[b] + 0.001f * rel, 0.8f);
    out[OUT_AT + b] = nat;
    float ctau = 0.5f * (1.f + 0.1f * ent);
    float etau = 0.3f * ctau + 0.7f * nat;
    float s = 1.f / (1.f + expf(-(rel - etau) * 10.f));
    out[OUT_SUR + b] = s;
    ws[WS_SUR + b] = s;
    float tsys = tau_sys_p[0];
    float tsc  = fmaxf(tsys, 0.01f);
    float tdyn = tsc / (1.f + s * expf(lls_p[0]));
    float teff = fminf(fmaxf(tdyn, 0.01f), 50.f);
    float dt   = fminf(fmaxf(0.1f / (teff + 0.1f), 0.01f), 0.5f);
    float u = 1.f / (1.f + expf(-(tsys - 0.01f) * 100.f));
    ws[WS_COEF_A + b] = u * (1.f - dt) + (1.f - u) * 0.05f;   // h coeff
    ws[WS_COEF_B + b] = u * dt + (1.f - u) * 0.95f;           // h_target coeff
    float lam = 0.01f * (1.f + s);
    ws[WS_CU + b] = 1.f - 0.1f * lam;
    ws[WS_CT + b] = 0.1f * lam;
    ws[WS_CH + b] = 0.1f * eta_p[0] * s;
}

// h_new
__global__ __launch_bounds__(256) void k_hnew(const float* __restrict__ h,
    const float* __restrict__ W, const float* __restrict__ Bm,
    const float* __restrict__ ws, float* __restrict__ out)
{
    int b = threadIdx.x & 63, ig = threadIdx.x >> 6;
    int hh = blockIdx.x * 8 + ig * 2;
    const float4* ep = (const float4*)(ws + WS_ERR + b * II);
    const float4* xp = (const float4*)(ws + WS_XN + b * II);
    const float4* w0 = (const float4*)(W + hh * II);
    const float4* w1 = (const float4*)(W + (hh + 1) * II);
    const float4* m0 = (const float4*)(Bm + hh * II);
    const float4* m1 = (const float4*)(Bm + (hh + 1) * II);
    float aw0 = 0, aw1 = 0, ab0 = 0, ab1 = 0;
    #pragma unroll 4
    for (int t = 0; t < 128; ++t) {
        float4 e = ep[t], xn = xp[t];
        float4 v0 = w0[t], v1 = w1[t], u0 = m0[t], u1 = m1[t];
        aw0 += e.x*v0.x + e.y*v0.y + e.z*v0.z + e.w*v0.w;
        aw1 += e.x*v1.x + e.y*v1.y + e.z*v1.z + e.w*v1.w;
        ab0 += xn.x*u0.x + xn.y*u0.y + xn.z*u0.z + xn.w*u0.w;
        ab1 += xn.x*u1.x + xn.y*u1.y + xn.z*u1.z + xn.w*u1.w;
    }
    float s = ws[WS_SUR + b];
    float A = ws[WS_COEF_A + b], Bc = ws[WS_COEF_B + b];
    float h0 = h[b * HH + hh], h1 = h[b * HH + hh + 1];
    float ht0 = tanhf(0.7f * h0 + 0.2f * ab0 + 0.3f * s * aw0);
    float ht1 = tanhf(0.7f * h1 + 0.2f * ab1 + 0.3f * s * aw1);
    out[OUT_HNEW + b * HH + hh]     = A * h0 + Bc * ht0;
    out[OUT_HNEW + b * HH + hh + 1] = A * h1 + Bc * ht1;
}

// U pass 1: unscaled U_new + per-b fro^2 accumulation
__global__ __launch_bounds__(256) void k_upd(const float* __restrict__ U,
    const float* __restrict__ Ut, const float* __restrict__ h,
    const float* __restrict__ ws, float* __restrict__ uout, float* __restrict__ fro2)
{
    __shared__ float red[4];
    int gid = blockIdx.x * 256 + threadIdx.x;
    int b = blockIdx.x >> 7;                 // 128 blocks per batch
    int e0 = (gid << 2) & (131072 - 1);      // element offset within batch
    int hh = e0 >> 6;
    int r  = e0 & 63;
    const float4 u4 = ((const float4*)U)[gid];
    const float4 t4 = ((const float4*)Ut)[gid];
    const float4 ev4 = *(const float4*)(ws + WS_EVEC + b * RR + r);
    float hv = h[b * HH + hh];
    float a  = ws[WS_CU + b];
    float tc = ws[WS_CT + b];
    float c  = ws[WS_CH + b] * hv;
    float4 un;
    un.x = a * u4.x + tc * t4.x + c * ev4.x;
    un.y = a * u4.y + tc * t4.y + c * ev4.y;
    un.z = a * u4.z + tc * t4.z + c * ev4.z;
    un.w = a * u4.w + tc * t4.w + c * ev4.w;
    ((float4*)uout)[gid] = un;
    float p = un.x*un.x + un.y*un.y + un.z*un.z + un.w*un.w;
    p = wave_reduce_sum(p);
    int lane = threadIdx.x & 63, wid = threadIdx.x >> 6;
    if (lane == 0) red[wid] = p;
    __syncthreads();
    if (threadIdx.x == 0) atomicAdd(&fro2[b], red[0] + red[1] + red[2] + red[3]);
}

// U pass 2: rescale
__global__ __launch_bounds__(256) void k_uscale(float* __restrict__ uout,
                                                const float* __restrict__ fro2)
{
    int gid = blockIdx.x * 256 + threadIdx.x;
    int b = gid >> 15;                       // 32768 float4 per batch
    float f = fro2[b];
    float s = fminf(1.0f / (sqrtf(f) + 1e-6f), 1.5f);
    float4 v = ((float4*)uout)[gid];
    v.x *= s; v.y *= s; v.z *= s; v.w *= s;
    ((float4*)uout)[gid] = v;
}

extern "C" void kernel_launch(void* const* d_in, const int* in_sizes, int n_in,
                              void* d_out, int out_size, void* d_ws, size_t ws_size,
                              hipStream_t stream) {
    const float* x   = (const float*)d_in[0];
    const float* h   = (const float*)d_in[1];
    const float* U   = (const float*)d_in[2];
    const float* Ut  = (const float*)d_in[3];
    const float* em  = (const float*)d_in[4];
    const float* ev  = (const float*)d_in[5];
    const float* at  = (const float*)d_in[6];
    const float* C   = (const float*)d_in[7];
    const float* W   = (const float*)d_in[8];
    const float* Bm  = (const float*)d_in[9];
    const float* V   = (const float*)d_in[10];
    const float* eta = (const float*)d_in[11];
    const float* tau = (const float*)d_in[12];
    const float* lls = (const float*)d_in[13];
    float* out = (float*)d_out;
    float* ws  = (float*)d_ws;

    hipMemsetAsync(ws + WS_PRED, 0, BB * II * sizeof(float), stream);
    hipMemsetAsync(ws + WS_FRO2, 0, BB * sizeof(float), stream);

    k_pred   <<<256, 256, 0, stream>>>(h, C, ws + WS_PRED);
    k_combine<<<64,  256, 0, stream>>>(x, em, ev, V, ws, out);
    k_scalars<<<1,   64,  0, stream>>>(at, eta, tau, lls, ws, out);
    k_hnew   <<<256, 256, 0, stream>>>(h, W, Bm, ws, out);
    k_upd    <<<8192,256, 0, stream>>>(U, Ut, h, ws, out + OUT_U, ws + WS_FRO2);
    k_uscale <<<8192,256, 0, stream>>>(out + OUT_U, ws + WS_FRO2);
}